// Round 20
// baseline (5912.891 us; speedup 1.0000x reference)
//
#include <hip/hip_runtime.h>

// CustomGRU: B=256, T=1024, I=128, H=256.  out = concat(output[B,T,H], h_last[B,H]) f32.
//
// R20 = R16 skeleton with 2-WG groups (128 groups x 2 members, same XCD residue):
// WG = 2 batches x 128 units; thread = 8 units x 3 gates x 8-k slice = 192 pinned
// W f32 (96 f32x2; pin mechanism proven at 48/96 regs, budget 256 at waves 2,2).
// Halves exchange fan-in (4->2) and poll slots (1/thread). Accumulators collapse
// per-fam immediately (peak ~245 VGPR). Reduce: batch on lane bit0, stages
// xor1(batch-redistributing) xor2 ror4 ror8 xor16 (all R16-proven DPP/swizzle ops).

#define B_SZ 256
#define T_SZ 1024
#define H_SZ 256
#define G3   768
#define NGRP 128
#define SPIN_MAX (1 << 21)
#define HROW 288

typedef __attribute__((ext_vector_type(2))) float f32x2;

template<int CTRL>
__device__ __forceinline__ float dppx(float s) {
    return __int_as_float(
        __builtin_amdgcn_update_dpp(0, __float_as_int(s), CTRL, 0xF, 0xF, true));
}
template<int MASK>
__device__ __forceinline__ float swzx(float s) {
    return __int_as_float(__builtin_amdgcn_ds_swizzle(__float_as_int(s), MASK));
}
__device__ __forceinline__ f32x2 pkfma(f32x2 a, f32x2 b, f32x2 c) {
    f32x2 d;
    asm("v_pk_fma_f32 %0, %1, %2, %3" : "=v"(d) : "v"(a), "v"(b), "v"(c));
    return d;
}

// h position map: word k -> k + 4*(k>>5)  (injective; 4-word pad per 32 words)
static __device__ __forceinline__ int hpos(int k) { return k + 4 * (k >> 5); }

// slot: [g 128][par 2][n 2][unit 256] u64 = (ver<<32)|f32bits
static __device__ __forceinline__ size_t xsl(int g, int par, int n, int u) {
    return (((size_t)g * 2 + par) * 2 + n) * 256 + u;
}

// ---------------- prep ----------------
__global__ void prep_kernel(const float* __restrict__ h0,
                            unsigned long long* __restrict__ xch) {
    int tid = blockIdx.x * blockDim.x + threadIdx.x;
    if (tid < B_SZ * H_SZ) {
        int b = tid >> 8, u = tid & 255;
        int g = b >> 1, n = b & 1;
        unsigned long long val = (unsigned long long)__float_as_uint(h0[tid]);
        xch[xsl(g, 0, n, u)] = val;
        xch[xsl(g, 1, n, u)] = val;
    }
}

// ---------------- phase 1: gx = x @ W_ih^T (unchanged since R9) ----------------
__global__ __launch_bounds__(256) void gemm_x_kernel(
    const float* __restrict__ x, const float* __restrict__ wih,
    float* __restrict__ gx, int c, int tcShift)
{
    __shared__ __align__(16) float xs[64][132];
    __shared__ __align__(16) float ws[128][68];
    const int TC = 1 << tcShift;
    const int t  = threadIdx.x;
    const int bx = blockIdx.x, by = blockIdx.y;

#pragma unroll
    for (int i = 0; i < 8; ++i) {
        int f4 = t + i * 256;
        int r  = f4 >> 5, c4 = (f4 & 31) * 4;
        int rho = bx * 64 + r;
        int b = rho >> tcShift, u = rho & (TC - 1);
        float4 v = *(const float4*)(x + ((size_t)b * T_SZ + (size_t)c * TC + u) * 128 + c4);
        *(float4*)&xs[r][c4] = v;
    }

    const int gl = t & 31;
    const int rl = t >> 5;
    float acc[8][4];
#pragma unroll
    for (int i = 0; i < 8; ++i)
#pragma unroll
        for (int jj = 0; jj < 4; ++jj) acc[i][jj] = 0.f;

    for (int kb = 0; kb < 2; ++kb) {
        __syncthreads();
#pragma unroll
        for (int i = 0; i < 8; ++i) {
            int f4 = t + i * 256;
            int row = f4 >> 4, c4 = (f4 & 15) * 4;
            float4 v = *(const float4*)(wih + (size_t)(by * 128 + row) * 128 + kb * 64 + c4);
            *(float4*)&ws[row][c4] = v;
        }
        __syncthreads();

#pragma unroll 4
        for (int k4 = 0; k4 < 16; ++k4) {
            float4 wv0 = *(const float4*)&ws[gl     ][k4 * 4];
            float4 wv1 = *(const float4*)&ws[gl + 32][k4 * 4];
            float4 wv2 = *(const float4*)&ws[gl + 64][k4 * 4];
            float4 wv3 = *(const float4*)&ws[gl + 96][k4 * 4];
#pragma unroll
            for (int rr = 0; rr < 8; ++rr) {
                float4 xv = *(const float4*)&xs[rl + rr * 8][kb * 64 + k4 * 4];
                acc[rr][0] = fmaf(xv.w, wv0.w, fmaf(xv.z, wv0.z, fmaf(xv.y, wv0.y, fmaf(xv.x, wv0.x, acc[rr][0]))));
                acc[rr][1] = fmaf(xv.w, wv1.w, fmaf(xv.z, wv1.z, fmaf(xv.y, wv1.y, fmaf(xv.x, wv1.x, acc[rr][1]))));
                acc[rr][2] = fmaf(xv.w, wv2.w, fmaf(xv.z, wv2.z, fmaf(xv.y, wv2.y, fmaf(xv.x, wv2.x, acc[rr][2]))));
                acc[rr][3] = fmaf(xv.w, wv3.w, fmaf(xv.z, wv3.z, fmaf(xv.y, wv3.y, fmaf(xv.x, wv3.x, acc[rr][3]))));
            }
        }
    }

#pragma unroll
    for (int rr = 0; rr < 8; ++rr) {
        size_t base = (size_t)(bx * 64 + rl + rr * 8) * G3 + by * 128 + gl;
#pragma unroll
        for (int gi = 0; gi < 4; ++gi)
            gx[base + 32 * gi] = acc[rr][gi];
    }
}

#define PIN2(v) asm volatile("" : "+v"(v));

// ---------------- phase 2: recurrence ----------------
// grid 256 x 512. g = bid&127, m = bid>>7 (members bid=g, g+128: same XCD residue),
// u0 = 128m. Thread: q = t>>5 (unit octet uo = u0+8q), p = t&31 (8-k slice),
// pb = p&1 (batch). fam = gate*8 + e (e = unit in octet). s[fam] = batch pb sum.
__global__ __launch_bounds__(512)
__attribute__((amdgpu_waves_per_eu(2, 2)))
void gru_kernel(
    const float* __restrict__ gx, const float* __restrict__ whh,
    const float* __restrict__ bih, const float* __restrict__ bhh,
    unsigned long long* __restrict__ xch, float* __restrict__ out,
    int gbase, int tc, int isLast)
{
    __shared__ __align__(16) float hl[2][HROW];
    __shared__ __align__(16) float hst[2][128];

    const int t   = threadIdx.x;
    const int bid = blockIdx.x;
    const int g   = bid & 127;
    const int m   = bid >> 7;
    const int u0  = m * 128;
    const int q   = t >> 5;
    const int p   = t & 31;
    const int pb  = p & 1;
    const int uo  = u0 + 8 * q;
    const int k0  = 8 * p;

    // ---- W: 24 fams (3 gates x 8 units) x 8 k = 96 pinned f32x2 (192 f32) ----
    f32x2 wf[24][4];
#pragma unroll
    for (int gate = 0; gate < 3; ++gate) {
#pragma unroll
        for (int e = 0; e < 8; ++e) {
            const float* wr = whh + (size_t)(gate * 256 + uo + e) * H_SZ + k0;
            float4 va = *(const float4*)(wr);
            float4 vb = *(const float4*)(wr + 4);
            wf[gate * 8 + e][0] = (f32x2){va.x, va.y};
            wf[gate * 8 + e][1] = (f32x2){va.z, va.w};
            wf[gate * 8 + e][2] = (f32x2){vb.x, vb.y};
            wf[gate * 8 + e][3] = (f32x2){vb.z, vb.w};
        }
    }
#pragma unroll
    for (int f = 0; f < 24; ++f) {
        PIN2(wf[f][0]) PIN2(wf[f][1]) PIN2(wf[f][2]) PIN2(wf[f][3])
    }

    // ---- gate-lane invariants: lanes p<16; e = p>>1, unit ue = uo+e, batch pb ----
    const bool act = (p < 16);
    const int  e   = p >> 1;
    const int  ue  = uo + e;
    float bsr = 0.f, bsz = 0.f, bsn = 0.f;
    const float* gxp = nullptr;
    if (act) {
        bsr = bih[ue]       + bhh[ue];
        bsz = bih[256 + ue] + bhh[256 + ue];
        bsn = bih[512 + ue] + bhh[512 + ue];
        gxp = gx + ((size_t)(2 * g + pb) * tc) * G3 + ue;
    }

    // gather mapping: thread polls 1 slot (batch n_t, unit un)
    const int n_t  = t >> 8;
    const int un   = t & 255;
    const int wofs = hpos(un);
    const int Wd   = hpos(k0);
    const int pue  = hpos(ue);
    // out-store mapping (t<64): batch n_o, float4 chunk f_o
    const int n_o = t >> 5, f_o = t & 31;

    // preload gx(u=0)
    float gxr = 0.f, gxz = 0.f, gxn = 0.f;
    if (act) { gxr = gxp[0]; gxz = gxp[256]; gxn = gxp[512]; }

#pragma unroll 1
    for (int u = 0; u < tc; ++u) {
        const int tg  = gbase + u;
        const int par = tg & 1;

        // ---- coalesced out-store for step u-1 ----
        if (u > 0 && t < 64) {
            float4 o;
            o.x = hst[n_o][4 * f_o];     o.y = hst[n_o][4 * f_o + 1];
            o.z = hst[n_o][4 * f_o + 2]; o.w = hst[n_o][4 * f_o + 3];
            *(float4*)(out + ((size_t)(2 * g + n_o) * T_SZ + (tg - 1)) * H_SZ + u0 + 4 * f_o) = o;
        }

        // ---- gather h(tg): poll 1 packed slot (data arrives with version) ----
        {
            unsigned long long* sb = xch + xsl(g, par, n_t, un);
            const unsigned want = (unsigned)tg;
            unsigned long long v = __hip_atomic_load(sb, __ATOMIC_RELAXED, __HIP_MEMORY_SCOPE_AGENT);
            int sp = 0;
            while ((unsigned)(v >> 32) != want && ++sp < SPIN_MAX) {
                __builtin_amdgcn_s_sleep(1);
                v = __hip_atomic_load(sb, __ATOMIC_RELAXED, __HIP_MEMORY_SCOPE_AGENT);
            }
            hl[n_t][wofs] = __uint_as_float((unsigned)v);
        }
        __syncthreads();

        // ---- prefetch gx(u+1) ----
        float pgr = 0.f, pgz = 0.f, pgn = 0.f;
        if (act && u + 1 < tc) {
            size_t go = (size_t)(u + 1) * G3;
            pgr = gxp[go]; pgz = gxp[go + 256]; pgn = gxp[go + 512];
        }

        // ---- matvec: 4 b128 reads (both batch rows), per-fam collapse ----
        float s[24];
        {
            const float* hrO = &hl[pb][Wd];       // own batch
            const float* hrX = &hl[pb ^ 1][Wd];   // other batch
            float4 o0 = *(const float4*)(hrO);
            float4 o1 = *(const float4*)(hrO + 4);
            float4 x0 = *(const float4*)(hrX);
            float4 x1 = *(const float4*)(hrX + 4);
            f32x2 ho0 = (f32x2){o0.x, o0.y}, ho1 = (f32x2){o0.z, o0.w};
            f32x2 ho2 = (f32x2){o1.x, o1.y}, ho3 = (f32x2){o1.z, o1.w};
            f32x2 hx0 = (f32x2){x0.x, x0.y}, hx1 = (f32x2){x0.z, x0.w};
            f32x2 hx2 = (f32x2){x1.x, x1.y}, hx3 = (f32x2){x1.z, x1.w};
            f32x2 z = (f32x2){0.f, 0.f};
#pragma unroll
            for (int f = 0; f < 24; ++f) {
                f32x2 aO = pkfma(ho0, wf[f][0],
                           pkfma(ho1, wf[f][1],
                           pkfma(ho2, wf[f][2],
                           pkfma(ho3, wf[f][3], z))));
                f32x2 aX = pkfma(hx0, wf[f][0],
                           pkfma(hx1, wf[f][1],
                           pkfma(hx2, wf[f][2],
                           pkfma(hx3, wf[f][3], z))));
                float sO = aO.x + aO.y;           // own batch, slice p
                float sX = aX.x + aX.y;           // other batch, slice p
                // xor1: partner lane's sX is MY batch at slice p^1
                s[f] = sO + dppx<0xB1>(sX);
            }
        }

        // ---- reduce remaining k-slice bits: xor2, ror4+ror8, xor16 ----
#pragma unroll
        for (int f = 0; f < 24; ++f) {
            s[f] += dppx<0x4E>(s[f]);    // xor2
            s[f] += dppx<0x124>(s[f]);   // ror4
            s[f] += dppx<0x128>(s[f]);   // ror8
            s[f] += swzx<0x401F>(s[f]);  // xor16
        }

        // ---- gates + publish (lanes p<16: batch pb, unit ue = uo + e) ----
        if (act) {
            const bool e0 = (e & 1) != 0, e1 = (e & 2) != 0, e2 = (e & 4) != 0;
            float r01, r23, r45, r67, ry0, ry1, sr, sz, sn;
            r01 = e0 ? s[1] : s[0];  r23 = e0 ? s[3] : s[2];
            r45 = e0 ? s[5] : s[4];  r67 = e0 ? s[7] : s[6];
            ry0 = e1 ? r23 : r01;    ry1 = e1 ? r67 : r45;
            sr  = e2 ? ry1 : ry0;
            r01 = e0 ? s[9]  : s[8];  r23 = e0 ? s[11] : s[10];
            r45 = e0 ? s[13] : s[12]; r67 = e0 ? s[15] : s[14];
            ry0 = e1 ? r23 : r01;     ry1 = e1 ? r67 : r45;
            sz  = e2 ? ry1 : ry0;
            r01 = e0 ? s[17] : s[16]; r23 = e0 ? s[19] : s[18];
            r45 = e0 ? s[21] : s[20]; r67 = e0 ? s[23] : s[22];
            ry0 = e1 ? r23 : r01;     ry1 = e1 ? r67 : r45;
            sn  = e2 ? ry1 : ry0;

            float hold = hl[pb][pue];
            float ar = sr + gxr + bsr;
            float az = sz + gxz + bsz;
            float an = sn + gxn + bsn;
            float r  = 1.f / (1.f + expf(-ar));
            float z  = 1.f / (1.f + expf(-az));
            float nn = tanhf(r * an);
            float hn = (1.f - z) * hold + z * nn;

            hst[pb][ue - u0] = hn;
            __hip_atomic_store(xch + xsl(g, (tg + 1) & 1, pb, ue),
                               ((unsigned long long)(unsigned)(tg + 1) << 32) |
                               (unsigned long long)__float_as_uint(hn),
                               __ATOMIC_RELAXED, __HIP_MEMORY_SCOPE_AGENT);
        }
        gxr = pgr; gxz = pgz; gxn = pgn;
        __syncthreads();   // hl reads done; hst visible; publishes drained
    }

    // ---- flush last step's out rows (+ h_last) ----
    if (t < 64) {
        float4 o;
        o.x = hst[n_o][4 * f_o];     o.y = hst[n_o][4 * f_o + 1];
        o.z = hst[n_o][4 * f_o + 2]; o.w = hst[n_o][4 * f_o + 3];
        *(float4*)(out + ((size_t)(2 * g + n_o) * T_SZ + (gbase + tc - 1)) * H_SZ + u0 + 4 * f_o) = o;
        if (isLast)
            *(float4*)(out + (size_t)B_SZ * T_SZ * H_SZ
                           + (size_t)(2 * g + n_o) * H_SZ + u0 + 4 * f_o) = o;
    }
}

// ---------------- host ----------------
extern "C" void kernel_launch(void* const* d_in, const int* in_sizes, int n_in,
                              void* d_out, int out_size, void* d_ws, size_t ws_size,
                              hipStream_t stream) {
    const float* x   = (const float*)d_in[0];
    const float* h0  = (const float*)d_in[1];
    const float* wih = (const float*)d_in[2];
    const float* whh = (const float*)d_in[3];
    const float* bih = (const float*)d_in[4];
    const float* bhh = (const float*)d_in[5];
    float* out = (float*)d_out;

    char* ws = (char*)d_ws;
    const size_t xchB = (size_t)NGRP * 2 * 2 * 256 * 8;   // 1 MiB
    unsigned long long* xch = (unsigned long long*)ws;
    float* gxb = (float*)(ws + xchB);

    int tcShift = 10;
    while (tcShift > 0 &&
           xchB + (786432ull << tcShift) > ws_size) --tcShift;
    const int TC  = 1 << tcShift;
    const int nCh = T_SZ / TC;

    prep_kernel<<<dim3(256), dim3(256), 0, stream>>>(h0, xch);
    for (int c = 0; c < nCh; ++c) {
        gemm_x_kernel<<<dim3(B_SZ * TC / 64, 6), dim3(256), 0, stream>>>(
            x, wih, gxb, c, tcShift);
        gru_kernel<<<dim3(B_SZ), dim3(512), 0, stream>>>(
            gxb, whh, bih, bhh, xch, out, c * TC, TC, (c == nCh - 1) ? 1 : 0);
    }
}